// Round 1
// baseline (1810.216 us; speedup 1.0000x reference)
//
#include <hip/hip_runtime.h>

// SGC: 2-hop GCN-normalized propagation + dense 64x64 linear.
// N=100000 nodes, E=1000000 edges, D=64 features, fp32.

constexpr int kN = 100000;
constexpr int kD = 64;

// deg[i] = 1.0 (self-loop fill), then += w over edges with row==i
__global__ void k_init_deg(float* __restrict__ deg, int n) {
    int i = blockIdx.x * blockDim.x + threadIdx.x;
    if (i < n) deg[i] = 1.0f;
}

__global__ void k_scatter_deg(const int* __restrict__ row, const float* __restrict__ w,
                              float* __restrict__ deg, int E) {
    int e = blockIdx.x * blockDim.x + threadIdx.x;
    if (e < E) atomicAdd(&deg[row[e]], w[e]);
}

__global__ void k_dinv(float* __restrict__ deg, int n) {
    int i = blockIdx.x * blockDim.x + threadIdx.x;
    if (i < n) {
        float d = deg[i];
        deg[i] = (d > 0.0f) ? rsqrtf(d) : 0.0f;
    }
}

// wn[e] = dinv[row[e]] * w[e] * dinv[col[e]]
__global__ void k_wn(const int* __restrict__ row, const int* __restrict__ col,
                     const float* __restrict__ w, const float* __restrict__ dinv,
                     float* __restrict__ wn, int E) {
    int e = blockIdx.x * blockDim.x + threadIdx.x;
    if (e < E) wn[e] = dinv[row[e]] * w[e] * dinv[col[e]];
}

// h_out = dinv^2 * h_in  (the self-loop contribution), full init of h_out
__global__ void k_init_h(const float* __restrict__ h_in, const float* __restrict__ dinv,
                         float* __restrict__ h_out, int total) {
    int idx = blockIdx.x * blockDim.x + threadIdx.x;
    if (idx < total) {
        int i = idx >> 6;  // / kD
        float di = dinv[i];
        h_out[idx] = di * di * h_in[idx];
    }
}

// h_out[row[e]] += wn[e] * h_in[col[e]]  -- 16 lanes per edge, float4 each
__global__ void k_edge_hop(const int* __restrict__ row, const int* __restrict__ col,
                           const float* __restrict__ wn, const float* __restrict__ h_in,
                           float* h_out, int E) {
    int t = blockIdx.x * blockDim.x + threadIdx.x;
    int e = t >> 4;
    if (e >= E) return;
    int q = (t & 15) * 4;
    int c = col[e];
    int r = row[e];
    float wv = wn[e];
    const float4 hv = *reinterpret_cast<const float4*>(h_in + (size_t)c * kD + q);
    float* dst = h_out + (size_t)r * kD + q;
    atomicAdd(dst + 0, wv * hv.x);
    atomicAdd(dst + 1, wv * hv.y);
    atomicAdd(dst + 2, wv * hv.z);
    atomicAdd(dst + 3, wv * hv.w);
}

// out[r] = h[r] @ W + bias. May run in place (h == out): each thread reads its
// entire row into registers before storing (no cross-thread row sharing), so
// h/out intentionally NOT __restrict__.
__global__ __launch_bounds__(256) void k_gemm(const float* h, const float* __restrict__ W,
                                              const float* __restrict__ bias, float* out, int n) {
    __shared__ float Ws[kD * kD];
    __shared__ float bs[kD];
    for (int i = threadIdx.x; i < kD * kD; i += 256) Ws[i] = W[i];
    if (threadIdx.x < kD) bs[threadIdx.x] = bias[threadIdx.x];
    __syncthreads();
    int r = blockIdx.x * 256 + threadIdx.x;
    if (r >= n) return;
    float hr[kD];
    const float4* hp = reinterpret_cast<const float4*>(h + (size_t)r * kD);
#pragma unroll
    for (int k4 = 0; k4 < kD / 4; ++k4) {
        float4 v = hp[k4];
        hr[k4 * 4 + 0] = v.x;
        hr[k4 * 4 + 1] = v.y;
        hr[k4 * 4 + 2] = v.z;
        hr[k4 * 4 + 3] = v.w;
    }
    float4* op = reinterpret_cast<float4*>(out + (size_t)r * kD);
#pragma unroll
    for (int jb = 0; jb < kD / 4; ++jb) {
        float a0 = bs[jb * 4 + 0];
        float a1 = bs[jb * 4 + 1];
        float a2 = bs[jb * 4 + 2];
        float a3 = bs[jb * 4 + 3];
#pragma unroll
        for (int k = 0; k < kD; ++k) {
            float hv = hr[k];
            a0 = fmaf(hv, Ws[k * kD + jb * 4 + 0], a0);
            a1 = fmaf(hv, Ws[k * kD + jb * 4 + 1], a1);
            a2 = fmaf(hv, Ws[k * kD + jb * 4 + 2], a2);
            a3 = fmaf(hv, Ws[k * kD + jb * 4 + 3], a3);
        }
        op[jb] = make_float4(a0, a1, a2, a3);
    }
}

extern "C" void kernel_launch(void* const* d_in, const int* in_sizes, int n_in,
                              void* d_out, int out_size, void* d_ws, size_t ws_size,
                              hipStream_t stream) {
    const float* x    = (const float*)d_in[0];   // (N, 64)
    const int*   ei   = (const int*)d_in[1];     // (2, E)
    const float* ew   = (const float*)d_in[2];   // (E,)
    const float* W    = (const float*)d_in[3];   // (64, 64)
    const float* bias = (const float*)d_in[4];   // (64,)
    const int E = in_sizes[1] / 2;
    const int* row = ei;       // destination
    const int* col = ei + E;   // source

    // ws layout (floats): dinv[kN] | wn[E] | h1[kN*kD]   (~30 MB)
    float* ws   = (float*)d_ws;
    size_t off  = 0;
    float* dinv = ws + off; off += (size_t)((kN + 255) & ~255);
    float* wn   = ws + off; off += (size_t)((E + 255) & ~255);
    float* h1   = ws + off;
    float* h2   = (float*)d_out;  // hop-2 accumulates straight into d_out

    const int total = kN * kD;

    // normalization
    k_init_deg<<<(kN + 255) / 256, 256, 0, stream>>>(dinv, kN);
    k_scatter_deg<<<(E + 255) / 256, 256, 0, stream>>>(row, ew, dinv, E);
    k_dinv<<<(kN + 255) / 256, 256, 0, stream>>>(dinv, kN);
    k_wn<<<(E + 255) / 256, 256, 0, stream>>>(row, col, ew, dinv, wn, E);

    // hop 1: x -> h1
    k_init_h<<<(total + 255) / 256, 256, 0, stream>>>(x, dinv, h1, total);
    {
        long threads = (long)E * 16;
        k_edge_hop<<<(int)((threads + 255) / 256), 256, 0, stream>>>(row, col, wn, x, h1, E);
    }

    // hop 2: h1 -> h2 (= d_out)
    k_init_h<<<(total + 255) / 256, 256, 0, stream>>>(h1, dinv, h2, total);
    {
        long threads = (long)E * 16;
        k_edge_hop<<<(int)((threads + 255) / 256), 256, 0, stream>>>(row, col, wn, h1, h2, E);
    }

    // out = h2 @ W + bias, in place on d_out
    k_gemm<<<(kN + 255) / 256, 256, 0, stream>>>(h2, W, bias, (float*)d_out, kN);
}

// Round 2
// 338.316 us; speedup vs baseline: 5.3507x; 5.3507x over previous
//
#include <hip/hip_runtime.h>

// SGC: 2-hop GCN-normalized propagation + dense 64x64 linear.
// N=100000 nodes, E=1000000 edges, D=64 features, fp32.
// Strategy: build CSR (edges grouped by destination) per call via counting
// sort, then gather-style hops (1 wave per node, lane=feature) -> no fp
// atomics in the hot path.

constexpr int kN = 100000;
constexpr int kD = 64;

// counts=0, deg=1.0 (self-loop fill)
__global__ void k_init(int* __restrict__ counts, float* __restrict__ deg, int n) {
    int i = blockIdx.x * blockDim.x + threadIdx.x;
    if (i < n) { counts[i] = 0; deg[i] = 1.0f; }
}

// counts[row]++ ; deg[row] += w
__global__ void k_count(const int* __restrict__ row, const float* __restrict__ w,
                        int* __restrict__ counts, float* __restrict__ deg, int E) {
    int e = blockIdx.x * blockDim.x + threadIdx.x;
    if (e < E) {
        int r = row[e];
        atomicAdd(&counts[r], 1);
        atomicAdd(&deg[r], w[e]);
    }
}

__global__ void k_dinv(float* __restrict__ deg, int n) {
    int i = blockIdx.x * blockDim.x + threadIdx.x;
    if (i < n) {
        float d = deg[i];
        deg[i] = (d > 0.0f) ? rsqrtf(d) : 0.0f;
    }
}

// ---- hierarchical exclusive scan of counts (N=100k, chunk=1024) ----
__global__ __launch_bounds__(1024) void k_scan1(const int* __restrict__ counts,
                                                int* __restrict__ excl,
                                                int* __restrict__ partials, int n) {
    __shared__ int sh[1024];
    int t = threadIdx.x;
    int i = blockIdx.x * 1024 + t;
    int v = (i < n) ? counts[i] : 0;
    sh[t] = v;
    __syncthreads();
    for (int off = 1; off < 1024; off <<= 1) {
        int add = (t >= off) ? sh[t - off] : 0;
        __syncthreads();
        sh[t] += add;
        __syncthreads();
    }
    if (i < n) excl[i] = sh[t] - v;           // exclusive within chunk
    if (t == 1023) partials[blockIdx.x] = sh[t];  // chunk total
}

__global__ void k_scan2(int* __restrict__ partials, int nb) {
    if (threadIdx.x == 0 && blockIdx.x == 0) {
        int run = 0;
        for (int b = 0; b < nb; ++b) { int v = partials[b]; partials[b] = run; run += v; }
    }
}

__global__ __launch_bounds__(1024) void k_scan3(int* __restrict__ excl,
                                                const int* __restrict__ partials,
                                                int* __restrict__ cursor, int n, int E) {
    int i = blockIdx.x * 1024 + threadIdx.x;
    if (i < n) {
        int v = excl[i] + partials[blockIdx.x];
        excl[i] = v;
        cursor[i] = v;
    }
    if (i == 0) excl[n] = E;  // start[kN] = E
}

// place each edge into its destination bucket; store col index + normalized w
__global__ void k_scatter_csr(const int* __restrict__ row, const int* __restrict__ col,
                              const float* __restrict__ w, const float* __restrict__ dinv,
                              int* __restrict__ cursor, int* __restrict__ cidx,
                              float* __restrict__ cw, int E) {
    int e = blockIdx.x * blockDim.x + threadIdx.x;
    if (e >= E) return;
    int r = row[e], c = col[e];
    int pos = atomicAdd(&cursor[r], 1);
    cidx[pos] = c;
    cw[pos] = dinv[r] * w[e] * dinv[c];
}

// gather hop: 1 wave (64 lanes) per node, lane l = feature l.
// h_out[i] = dinv[i]^2 * h_in[i]  +  sum_j cw[j] * h_in[cidx[j]]
__global__ __launch_bounds__(256) void k_hop(const int* __restrict__ start,
                                             const int* __restrict__ cidx,
                                             const float* __restrict__ cw,
                                             const float* __restrict__ dinv,
                                             const float* __restrict__ h_in,
                                             float* __restrict__ h_out, int n) {
    int node = blockIdx.x * 4 + (threadIdx.x >> 6);
    int lane = threadIdx.x & 63;
    if (node >= n) return;
    float di = dinv[node];
    float acc = di * di * h_in[(size_t)node * kD + lane];
    int s = start[node], e = start[node + 1];
    int j = s;
    for (; j + 1 < e; j += 2) {  // unroll 2: issue both gathers before FMAs
        int c0 = cidx[j], c1 = cidx[j + 1];
        float w0 = cw[j], w1 = cw[j + 1];
        float v0 = h_in[(size_t)c0 * kD + lane];
        float v1 = h_in[(size_t)c1 * kD + lane];
        acc = fmaf(w0, v0, acc);
        acc = fmaf(w1, v1, acc);
    }
    if (j < e) {
        acc = fmaf(cw[j], h_in[(size_t)cidx[j] * kD + lane], acc);
    }
    h_out[(size_t)node * kD + lane] = acc;
}

// out[r] = h[r] @ W + bias. May run in place (h == out).
__global__ __launch_bounds__(256) void k_gemm(const float* h, const float* __restrict__ W,
                                              const float* __restrict__ bias, float* out, int n) {
    __shared__ float Ws[kD * kD];
    __shared__ float bs[kD];
    for (int i = threadIdx.x; i < kD * kD; i += 256) Ws[i] = W[i];
    if (threadIdx.x < kD) bs[threadIdx.x] = bias[threadIdx.x];
    __syncthreads();
    int r = blockIdx.x * 256 + threadIdx.x;
    if (r >= n) return;
    float hr[kD];
    const float4* hp = reinterpret_cast<const float4*>(h + (size_t)r * kD);
#pragma unroll
    for (int k4 = 0; k4 < kD / 4; ++k4) {
        float4 v = hp[k4];
        hr[k4 * 4 + 0] = v.x;
        hr[k4 * 4 + 1] = v.y;
        hr[k4 * 4 + 2] = v.z;
        hr[k4 * 4 + 3] = v.w;
    }
    float4* op = reinterpret_cast<float4*>(out + (size_t)r * kD);
#pragma unroll
    for (int jb = 0; jb < kD / 4; ++jb) {
        float a0 = bs[jb * 4 + 0];
        float a1 = bs[jb * 4 + 1];
        float a2 = bs[jb * 4 + 2];
        float a3 = bs[jb * 4 + 3];
#pragma unroll
        for (int k = 0; k < kD; ++k) {
            float hv = hr[k];
            a0 = fmaf(hv, Ws[k * kD + jb * 4 + 0], a0);
            a1 = fmaf(hv, Ws[k * kD + jb * 4 + 1], a1);
            a2 = fmaf(hv, Ws[k * kD + jb * 4 + 2], a2);
            a3 = fmaf(hv, Ws[k * kD + jb * 4 + 3], a3);
        }
        op[jb] = make_float4(a0, a1, a2, a3);
    }
}

extern "C" void kernel_launch(void* const* d_in, const int* in_sizes, int n_in,
                              void* d_out, int out_size, void* d_ws, size_t ws_size,
                              hipStream_t stream) {
    const float* x    = (const float*)d_in[0];   // (N, 64)
    const int*   ei   = (const int*)d_in[1];     // (2, E)
    const float* ew   = (const float*)d_in[2];   // (E,)
    const float* W    = (const float*)d_in[3];   // (64, 64)
    const float* bias = (const float*)d_in[4];   // (64,)
    const int E = in_sizes[1] / 2;
    const int* row = ei;       // destination
    const int* col = ei + E;   // source

    // ws layout (4-byte units):
    // dinv[kN] | counts[kN] | start[kN+1] | cursor[kN] | partials[256] |
    // cidx[E] | cw[E] | h1[kN*kD]            (~35 MB)
    char* ws = (char*)d_ws;
    auto alloc = [&](size_t elems) {
        char* p = ws;
        ws += ((elems * 4 + 1023) & ~(size_t)1023);
        return p;
    };
    float* dinv    = (float*)alloc(kN);
    int*   counts  = (int*)alloc(kN);
    int*   start   = (int*)alloc(kN + 1);
    int*   cursor  = (int*)alloc(kN);
    int*   partial = (int*)alloc(256);
    int*   cidx    = (int*)alloc(E);
    float* cw      = (float*)alloc(E);
    float* h1      = (float*)alloc((size_t)kN * kD);
    float* h2      = (float*)d_out;  // hop-2 writes straight into d_out

    const int NB = (kN + 1023) / 1024;  // scan chunks

    // --- normalization + CSR build ---
    k_init<<<(kN + 255) / 256, 256, 0, stream>>>(counts, dinv, kN);
    k_count<<<(E + 255) / 256, 256, 0, stream>>>(row, ew, counts, dinv, E);
    k_dinv<<<(kN + 255) / 256, 256, 0, stream>>>(dinv, kN);
    k_scan1<<<NB, 1024, 0, stream>>>(counts, start, partial, kN);
    k_scan2<<<1, 64, 0, stream>>>(partial, NB);
    k_scan3<<<NB, 1024, 0, stream>>>(start, partial, cursor, kN, E);
    k_scatter_csr<<<(E + 255) / 256, 256, 0, stream>>>(row, col, ew, dinv, cursor, cidx, cw, E);

    // --- 2 gather hops ---
    k_hop<<<(kN + 3) / 4, 256, 0, stream>>>(start, cidx, cw, dinv, x, h1, kN);
    k_hop<<<(kN + 3) / 4, 256, 0, stream>>>(start, cidx, cw, dinv, h1, h2, kN);

    // --- out = h2 @ W + bias, in place on d_out ---
    k_gemm<<<(kN + 255) / 256, 256, 0, stream>>>(h2, W, bias, (float*)d_out, kN);
}

// Round 3
// 337.804 us; speedup vs baseline: 5.3588x; 1.0015x over previous
//
#include <hip/hip_runtime.h>

// SGC: 2-hop GCN-normalized propagation + dense 64x64 linear.
// N=100000 nodes, E=1000000 edges, D=64 features, fp32.
// CSR build (counting sort, int atomics only) -> atomic-free gather hops.
// Hop 2 has the 64x64 GEMM + bias fused into its epilogue via wave shuffles.

constexpr int kN = 100000;
constexpr int kD = 64;

__global__ void k_zero(int* __restrict__ c, int n) {
    int i = blockIdx.x * blockDim.x + threadIdx.x;
    if (i < n) c[i] = 0;
}

// counts[row]++  (only int atomics; deg comes later from the CSR)
__global__ void k_count(const int* __restrict__ row, int* __restrict__ counts, int E) {
    int e = blockIdx.x * blockDim.x + threadIdx.x;
    if (e < E) atomicAdd(&counts[row[e]], 1);
}

// ---- hierarchical exclusive scan of counts (N=100k, chunk=1024) ----
__global__ __launch_bounds__(1024) void k_scan1(const int* __restrict__ counts,
                                                int* __restrict__ excl,
                                                int* __restrict__ partials, int n) {
    __shared__ int sh[1024];
    int t = threadIdx.x;
    int i = blockIdx.x * 1024 + t;
    int v = (i < n) ? counts[i] : 0;
    sh[t] = v;
    __syncthreads();
    for (int off = 1; off < 1024; off <<= 1) {
        int add = (t >= off) ? sh[t - off] : 0;
        __syncthreads();
        sh[t] += add;
        __syncthreads();
    }
    if (i < n) excl[i] = sh[t] - v;               // exclusive within chunk
    if (t == 1023) partials[blockIdx.x] = sh[t];  // chunk total
}

__global__ void k_scan2(int* __restrict__ partials, int nb) {
    if (threadIdx.x == 0 && blockIdx.x == 0) {
        int run = 0;
        for (int b = 0; b < nb; ++b) { int v = partials[b]; partials[b] = run; run += v; }
    }
}

__global__ __launch_bounds__(1024) void k_scan3(int* __restrict__ excl,
                                                const int* __restrict__ partials,
                                                int* __restrict__ cursor, int n, int E) {
    int i = blockIdx.x * 1024 + threadIdx.x;
    if (i < n) {
        int v = excl[i] + partials[blockIdx.x];
        excl[i] = v;
        cursor[i] = v;
    }
    if (i == 0) excl[n] = E;  // start[kN] = E
}

// place each edge into its destination bucket: ecw[pos] = {col, raw w}
__global__ void k_scatter(const int* __restrict__ row, const int* __restrict__ col,
                          const float* __restrict__ w, int* __restrict__ cursor,
                          int2* __restrict__ ecw, int E) {
    int e = blockIdx.x * blockDim.x + threadIdx.x;
    if (e >= E) return;
    int r = row[e];
    int pos = atomicAdd(&cursor[r], 1);
    int2 v;
    v.x = col[e];
    v.y = __float_as_int(w[e]);
    ecw[pos] = v;
}

// per node: deg = 1 + sum of raw w in its bucket; dinv = rsqrt(deg)
__global__ void k_deg(const int* __restrict__ start, const int2* __restrict__ ecw,
                      float* __restrict__ dinv, int n) {
    int i = blockIdx.x * blockDim.x + threadIdx.x;
    if (i >= n) return;
    int s = start[i], e = start[i + 1];
    float d = 1.0f;
    for (int j = s; j < e; ++j) d += __int_as_float(ecw[j].y);
    dinv[i] = (d > 0.0f) ? rsqrtf(d) : 0.0f;
}

// per node: normalize bucket weights in place: w' = dinv[i] * w * dinv[col]
__global__ void k_norm(const int* __restrict__ start, const float* __restrict__ dinv,
                       int2* __restrict__ ecw, int n) {
    int i = blockIdx.x * blockDim.x + threadIdx.x;
    if (i >= n) return;
    float di = dinv[i];
    int s = start[i], e = start[i + 1];
    for (int j = s; j < e; ++j) {
        int2 v = ecw[j];
        float wn = di * __int_as_float(v.y) * dinv[v.x];
        ecw[j].y = __float_as_int(wn);
    }
}

// gather hop: 1 wave (64 lanes) per node, lane l = feature l.
// h_out[i] = dinv[i]^2 * h_in[i] + sum_j w'[j] * h_in[cidx[j]]
__global__ __launch_bounds__(256) void k_hop(const int* __restrict__ start,
                                             const int2* __restrict__ ecw,
                                             const float* __restrict__ dinv,
                                             const float* __restrict__ h_in,
                                             float* __restrict__ h_out, int n) {
    int node = blockIdx.x * 4 + (threadIdx.x >> 6);
    int lane = threadIdx.x & 63;
    if (node >= n) return;
    float di = dinv[node];
    float acc = di * di * h_in[(size_t)node * kD + lane];
    int s = start[node], e = start[node + 1];
    int j = s;
    for (; j + 3 < e; j += 4) {
        int2 v0 = ecw[j], v1 = ecw[j + 1], v2 = ecw[j + 2], v3 = ecw[j + 3];
        float a0 = h_in[(size_t)v0.x * kD + lane];
        float a1 = h_in[(size_t)v1.x * kD + lane];
        float a2 = h_in[(size_t)v2.x * kD + lane];
        float a3 = h_in[(size_t)v3.x * kD + lane];
        acc = fmaf(__int_as_float(v0.y), a0, acc);
        acc = fmaf(__int_as_float(v1.y), a1, acc);
        acc = fmaf(__int_as_float(v2.y), a2, acc);
        acc = fmaf(__int_as_float(v3.y), a3, acc);
    }
    for (; j < e; ++j) {
        int2 v = ecw[j];
        acc = fmaf(__int_as_float(v.y), h_in[(size_t)v.x * kD + lane], acc);
    }
    h_out[(size_t)node * kD + lane] = acc;
}

// hop + fused 64x64 linear: out[node][lane] = bias[lane] + sum_k acc_k * W[k][lane]
__global__ __launch_bounds__(256) void k_hop_gemm(const int* __restrict__ start,
                                                  const int2* __restrict__ ecw,
                                                  const float* __restrict__ dinv,
                                                  const float* __restrict__ h_in,
                                                  const float* __restrict__ W,
                                                  const float* __restrict__ bias,
                                                  float* __restrict__ out, int n) {
    __shared__ float Ws[kD * kD];
    __shared__ float bs[kD];
    for (int i = threadIdx.x; i < kD * kD; i += 256) Ws[i] = W[i];
    if (threadIdx.x < kD) bs[threadIdx.x] = bias[threadIdx.x];
    __syncthreads();
    int node = blockIdx.x * 4 + (threadIdx.x >> 6);
    int lane = threadIdx.x & 63;
    if (node >= n) return;  // wave-uniform exit (1 wave = 1 node)
    float di = dinv[node];
    float acc = di * di * h_in[(size_t)node * kD + lane];
    int s = start[node], e = start[node + 1];
    int j = s;
    for (; j + 3 < e; j += 4) {
        int2 v0 = ecw[j], v1 = ecw[j + 1], v2 = ecw[j + 2], v3 = ecw[j + 3];
        float a0 = h_in[(size_t)v0.x * kD + lane];
        float a1 = h_in[(size_t)v1.x * kD + lane];
        float a2 = h_in[(size_t)v2.x * kD + lane];
        float a3 = h_in[(size_t)v3.x * kD + lane];
        acc = fmaf(__int_as_float(v0.y), a0, acc);
        acc = fmaf(__int_as_float(v1.y), a1, acc);
        acc = fmaf(__int_as_float(v2.y), a2, acc);
        acc = fmaf(__int_as_float(v3.y), a3, acc);
    }
    for (; j < e; ++j) {
        int2 v = ecw[j];
        acc = fmaf(__int_as_float(v.y), h_in[(size_t)v.x * kD + lane], acc);
    }
    // epilogue: row-vector times 64x64 matrix via wave broadcasts.
    // 4 partial accumulators to shorten the dependent FMA chain.
    float o0 = bs[lane], o1 = 0.0f, o2 = 0.0f, o3 = 0.0f;
#pragma unroll
    for (int k = 0; k < kD; k += 4) {
        float h0 = __shfl(acc, k + 0);
        float h1 = __shfl(acc, k + 1);
        float h2 = __shfl(acc, k + 2);
        float h3 = __shfl(acc, k + 3);
        o0 = fmaf(h0, Ws[(k + 0) * kD + lane], o0);
        o1 = fmaf(h1, Ws[(k + 1) * kD + lane], o1);
        o2 = fmaf(h2, Ws[(k + 2) * kD + lane], o2);
        o3 = fmaf(h3, Ws[(k + 3) * kD + lane], o3);
    }
    out[(size_t)node * kD + lane] = (o0 + o1) + (o2 + o3);
}

extern "C" void kernel_launch(void* const* d_in, const int* in_sizes, int n_in,
                              void* d_out, int out_size, void* d_ws, size_t ws_size,
                              hipStream_t stream) {
    const float* x    = (const float*)d_in[0];   // (N, 64)
    const int*   ei   = (const int*)d_in[1];     // (2, E)
    const float* ew   = (const float*)d_in[2];   // (E,)
    const float* W    = (const float*)d_in[3];   // (64, 64)
    const float* bias = (const float*)d_in[4];   // (64,)
    const int E = in_sizes[1] / 2;
    const int* row = ei;       // destination
    const int* col = ei + E;   // source

    // ws layout (bytes, 1KB-aligned chunks):
    // counts[kN] | start[kN+1] | cursor[kN] | partials[256] | dinv[kN] |
    // ecw[E] (int2) | h1[kN*kD]                       (~36 MB)
    char* ws = (char*)d_ws;
    auto alloc = [&](size_t bytes) {
        char* p = ws;
        ws += ((bytes + 1023) & ~(size_t)1023);
        return p;
    };
    int*   counts  = (int*)alloc(sizeof(int) * kN);
    int*   start   = (int*)alloc(sizeof(int) * (kN + 1));
    int*   cursor  = (int*)alloc(sizeof(int) * kN);
    int*   partial = (int*)alloc(sizeof(int) * 256);
    float* dinv    = (float*)alloc(sizeof(float) * kN);
    int2*  ecw     = (int2*)alloc(sizeof(int2) * (size_t)E);
    float* h1      = (float*)alloc(sizeof(float) * (size_t)kN * kD);

    const int NB = (kN + 1023) / 1024;  // scan chunks

    // --- CSR build ---
    k_zero<<<(kN + 255) / 256, 256, 0, stream>>>(counts, kN);
    k_count<<<(E + 255) / 256, 256, 0, stream>>>(row, counts, E);
    k_scan1<<<NB, 1024, 0, stream>>>(counts, start, partial, kN);
    k_scan2<<<1, 64, 0, stream>>>(partial, NB);
    k_scan3<<<NB, 1024, 0, stream>>>(start, partial, cursor, kN, E);
    k_scatter<<<(E + 255) / 256, 256, 0, stream>>>(row, col, ew, cursor, ecw, E);

    // --- normalization from the CSR (no atomics) ---
    k_deg<<<(kN + 255) / 256, 256, 0, stream>>>(start, ecw, dinv, kN);
    k_norm<<<(kN + 255) / 256, 256, 0, stream>>>(start, dinv, ecw, kN);

    // --- hop 1: x -> h1 ; hop 2 + GEMM: h1 -> d_out ---
    k_hop<<<(kN + 3) / 4, 256, 0, stream>>>(start, ecw, dinv, x, h1, kN);
    k_hop_gemm<<<(kN + 3) / 4, 256, 0, stream>>>(start, ecw, dinv, h1, W, bias,
                                                 (float*)d_out, kN);
}

// Round 4
// 279.491 us; speedup vs baseline: 6.4768x; 1.2086x over previous
//
#include <hip/hip_runtime.h>

// SGC: out = A_norm^2 (x W) + bias   (exploits linearity: A^2 x W = A^2 (xW)).
// N=100000 nodes, E=1000000 edges, D=64 features, fp32 in/out.
// CSR build (counting sort, int atomics only) -> atomic-free gather hops.
// Intermediates y=xW and h1 stored bf16 to halve gather traffic; dinv[col]
// normalization folded into the hops (no k_norm pass).

constexpr int kN = 100000;
constexpr int kD = 64;

__device__ __forceinline__ float bf2f(unsigned short u) {
    return __uint_as_float(((unsigned)u) << 16);
}
__device__ __forceinline__ unsigned short f2bf(float f) {  // RNE
    unsigned b = __float_as_uint(f);
    b += 0x7FFF + ((b >> 16) & 1);
    return (unsigned short)(b >> 16);
}

__global__ void k_zero(int* __restrict__ c, int n) {
    int i = blockIdx.x * blockDim.x + threadIdx.x;
    if (i < n) c[i] = 0;
}

// counts[row]++
__global__ void k_count(const int* __restrict__ row, int* __restrict__ counts, int E) {
    int e = blockIdx.x * blockDim.x + threadIdx.x;
    if (e < E) atomicAdd(&counts[row[e]], 1);
}

// ---- hierarchical exclusive scan of counts (N=100k, chunk=1024) ----
__global__ __launch_bounds__(1024) void k_scan1(const int* __restrict__ counts,
                                                int* __restrict__ excl,
                                                int* __restrict__ partials, int n) {
    __shared__ int sh[1024];
    int t = threadIdx.x;
    int i = blockIdx.x * 1024 + t;
    int v = (i < n) ? counts[i] : 0;
    sh[t] = v;
    __syncthreads();
    for (int off = 1; off < 1024; off <<= 1) {
        int add = (t >= off) ? sh[t - off] : 0;
        __syncthreads();
        sh[t] += add;
        __syncthreads();
    }
    if (i < n) excl[i] = sh[t] - v;               // exclusive within chunk
    if (t == 1023) partials[blockIdx.x] = sh[t];  // chunk total
}

// parallel exclusive scan of the (<=128) chunk totals, one block
__global__ __launch_bounds__(128) void k_scan2(int* __restrict__ partials, int nb) {
    __shared__ int sh[128];
    int t = threadIdx.x;
    int v = (t < nb) ? partials[t] : 0;
    sh[t] = v;
    __syncthreads();
    for (int off = 1; off < 128; off <<= 1) {
        int add = (t >= off) ? sh[t - off] : 0;
        __syncthreads();
        sh[t] += add;
        __syncthreads();
    }
    if (t < nb) partials[t] = sh[t] - v;  // exclusive
}

__global__ __launch_bounds__(1024) void k_scan3(int* __restrict__ excl,
                                                const int* __restrict__ partials,
                                                int* __restrict__ cursor, int n, int E) {
    int i = blockIdx.x * 1024 + threadIdx.x;
    if (i < n) {
        int v = excl[i] + partials[blockIdx.x];
        excl[i] = v;
        cursor[i] = v;
    }
    if (i == 0) excl[n] = E;  // start[kN] = E
}

// place each edge into its destination bucket: ecw[pos] = {col, raw w}
__global__ void k_scatter(const int* __restrict__ row, const int* __restrict__ col,
                          const float* __restrict__ w, int* __restrict__ cursor,
                          int2* __restrict__ ecw, int E) {
    int e = blockIdx.x * blockDim.x + threadIdx.x;
    if (e >= E) return;
    int r = row[e];
    int pos = atomicAdd(&cursor[r], 1);
    int2 v;
    v.x = col[e];
    v.y = __float_as_int(w[e]);
    ecw[pos] = v;
}

// per node: deg = 1 + sum of raw w in its bucket; dinv = rsqrt(deg)
__global__ void k_deg(const int* __restrict__ start, const int2* __restrict__ ecw,
                      float* __restrict__ dinv, int n) {
    int i = blockIdx.x * blockDim.x + threadIdx.x;
    if (i >= n) return;
    int s = start[i], e = start[i + 1];
    float d = 1.0f;
    for (int j = s; j < e; ++j) d += __int_as_float(ecw[j].y);
    dinv[i] = (d > 0.0f) ? rsqrtf(d) : 0.0f;
}

// y = x @ W  (fp32 in, bf16 out). thread = row, W staged in LDS.
__global__ __launch_bounds__(256) void k_xw(const float* __restrict__ x,
                                            const float* __restrict__ W,
                                            unsigned short* __restrict__ y, int n) {
    __shared__ float Ws[kD * kD];
    for (int i = threadIdx.x; i < kD * kD; i += 256) Ws[i] = W[i];
    __syncthreads();
    int r = blockIdx.x * 256 + threadIdx.x;
    if (r >= n) return;
    float hr[kD];
    const float4* hp = reinterpret_cast<const float4*>(x + (size_t)r * kD);
#pragma unroll
    for (int k4 = 0; k4 < kD / 4; ++k4) {
        float4 v = hp[k4];
        hr[k4 * 4 + 0] = v.x;
        hr[k4 * 4 + 1] = v.y;
        hr[k4 * 4 + 2] = v.z;
        hr[k4 * 4 + 3] = v.w;
    }
    ushort4* op = reinterpret_cast<ushort4*>(y + (size_t)r * kD);
#pragma unroll
    for (int jb = 0; jb < kD / 4; ++jb) {
        float a0 = 0.0f, a1 = 0.0f, a2 = 0.0f, a3 = 0.0f;
#pragma unroll
        for (int k = 0; k < kD; ++k) {
            float hv = hr[k];
            a0 = fmaf(hv, Ws[k * kD + jb * 4 + 0], a0);
            a1 = fmaf(hv, Ws[k * kD + jb * 4 + 1], a1);
            a2 = fmaf(hv, Ws[k * kD + jb * 4 + 2], a2);
            a3 = fmaf(hv, Ws[k * kD + jb * 4 + 3], a3);
        }
        ushort4 o;
        o.x = f2bf(a0); o.y = f2bf(a1); o.z = f2bf(a2); o.w = f2bf(a3);
        op[jb] = o;
    }
}

// hop1: h_out(bf16) = D^-1/2 (A+I) D^-1/2 h_in(bf16).  1 wave/node, lane=feature.
// acc = dinv[i]*h[i] + sum_j (w_j*dinv[col_j])*h[col_j];  h_out = dinv[i]*acc
__global__ __launch_bounds__(256) void k_hop1(const int* __restrict__ start,
                                              const int2* __restrict__ ecw,
                                              const float* __restrict__ dinv,
                                              const unsigned short* __restrict__ h_in,
                                              unsigned short* __restrict__ h_out, int n) {
    int node = blockIdx.x * 4 + (threadIdx.x >> 6);
    int lane = threadIdx.x & 63;
    if (node >= n) return;
    float di = dinv[node];
    float acc = di * bf2f(h_in[(size_t)node * kD + lane]);
    int s = start[node], e = start[node + 1];
    int j = s;
    for (; j + 3 < e; j += 4) {
        int2 v0 = ecw[j], v1 = ecw[j + 1], v2 = ecw[j + 2], v3 = ecw[j + 3];
        float w0 = __int_as_float(v0.y) * dinv[v0.x];
        float w1 = __int_as_float(v1.y) * dinv[v1.x];
        float w2 = __int_as_float(v2.y) * dinv[v2.x];
        float w3 = __int_as_float(v3.y) * dinv[v3.x];
        float a0 = bf2f(h_in[(size_t)v0.x * kD + lane]);
        float a1 = bf2f(h_in[(size_t)v1.x * kD + lane]);
        float a2 = bf2f(h_in[(size_t)v2.x * kD + lane]);
        float a3 = bf2f(h_in[(size_t)v3.x * kD + lane]);
        acc = fmaf(w0, a0, acc);
        acc = fmaf(w1, a1, acc);
        acc = fmaf(w2, a2, acc);
        acc = fmaf(w3, a3, acc);
    }
    for (; j < e; ++j) {
        int2 v = ecw[j];
        acc = fmaf(__int_as_float(v.y) * dinv[v.x],
                   bf2f(h_in[(size_t)v.x * kD + lane]), acc);
    }
    h_out[(size_t)node * kD + lane] = f2bf(di * acc);
}

// hop2: out(fp32) = D^-1/2 (A+I) D^-1/2 h_in(bf16) + bias
__global__ __launch_bounds__(256) void k_hop2(const int* __restrict__ start,
                                              const int2* __restrict__ ecw,
                                              const float* __restrict__ dinv,
                                              const unsigned short* __restrict__ h_in,
                                              const float* __restrict__ bias,
                                              float* __restrict__ out, int n) {
    int node = blockIdx.x * 4 + (threadIdx.x >> 6);
    int lane = threadIdx.x & 63;
    if (node >= n) return;
    float di = dinv[node];
    float acc = di * bf2f(h_in[(size_t)node * kD + lane]);
    int s = start[node], e = start[node + 1];
    int j = s;
    for (; j + 3 < e; j += 4) {
        int2 v0 = ecw[j], v1 = ecw[j + 1], v2 = ecw[j + 2], v3 = ecw[j + 3];
        float w0 = __int_as_float(v0.y) * dinv[v0.x];
        float w1 = __int_as_float(v1.y) * dinv[v1.x];
        float w2 = __int_as_float(v2.y) * dinv[v2.x];
        float w3 = __int_as_float(v3.y) * dinv[v3.x];
        float a0 = bf2f(h_in[(size_t)v0.x * kD + lane]);
        float a1 = bf2f(h_in[(size_t)v1.x * kD + lane]);
        float a2 = bf2f(h_in[(size_t)v2.x * kD + lane]);
        float a3 = bf2f(h_in[(size_t)v3.x * kD + lane]);
        acc = fmaf(w0, a0, acc);
        acc = fmaf(w1, a1, acc);
        acc = fmaf(w2, a2, acc);
        acc = fmaf(w3, a3, acc);
    }
    for (; j < e; ++j) {
        int2 v = ecw[j];
        acc = fmaf(__int_as_float(v.y) * dinv[v.x],
                   bf2f(h_in[(size_t)v.x * kD + lane]), acc);
    }
    out[(size_t)node * kD + lane] = fmaf(di, acc, bias[lane]);
}

extern "C" void kernel_launch(void* const* d_in, const int* in_sizes, int n_in,
                              void* d_out, int out_size, void* d_ws, size_t ws_size,
                              hipStream_t stream) {
    const float* x    = (const float*)d_in[0];   // (N, 64)
    const int*   ei   = (const int*)d_in[1];     // (2, E)
    const float* ew   = (const float*)d_in[2];   // (E,)
    const float* W    = (const float*)d_in[3];   // (64, 64)
    const float* bias = (const float*)d_in[4];   // (64,)
    const int E = in_sizes[1] / 2;
    const int* row = ei;       // destination
    const int* col = ei + E;   // source

    // ws layout (1KB-aligned): counts[kN] | start[kN+1] | cursor[kN] |
    // partials[128] | dinv[kN] | ecw[E] int2 | y[kN*kD] bf16 | h1[kN*kD] bf16
    // total ~= 35 MB
    char* ws = (char*)d_ws;
    auto alloc = [&](size_t bytes) {
        char* p = ws;
        ws += ((bytes + 1023) & ~(size_t)1023);
        return p;
    };
    int*            counts  = (int*)alloc(sizeof(int) * kN);
    int*            start   = (int*)alloc(sizeof(int) * (kN + 1));
    int*            cursor  = (int*)alloc(sizeof(int) * kN);
    int*            partial = (int*)alloc(sizeof(int) * 128);
    float*          dinv    = (float*)alloc(sizeof(float) * kN);
    int2*           ecw     = (int2*)alloc(sizeof(int2) * (size_t)E);
    unsigned short* y       = (unsigned short*)alloc(sizeof(short) * (size_t)kN * kD);
    unsigned short* h1      = (unsigned short*)alloc(sizeof(short) * (size_t)kN * kD);

    const int NB = (kN + 1023) / 1024;  // 98 scan chunks (<=128 for k_scan2)

    // --- dense linear first: y = x @ W (bf16) ---
    k_xw<<<(kN + 255) / 256, 256, 0, stream>>>(x, W, y, kN);

    // --- CSR build ---
    k_zero<<<(kN + 255) / 256, 256, 0, stream>>>(counts, kN);
    k_count<<<(E + 255) / 256, 256, 0, stream>>>(row, counts, E);
    k_scan1<<<NB, 1024, 0, stream>>>(counts, start, partial, kN);
    k_scan2<<<1, 128, 0, stream>>>(partial, NB);
    k_scan3<<<NB, 1024, 0, stream>>>(start, partial, cursor, kN, E);
    k_scatter<<<(E + 255) / 256, 256, 0, stream>>>(row, col, ew, cursor, ecw, E);
    k_deg<<<(kN + 255) / 256, 256, 0, stream>>>(start, ecw, dinv, kN);

    // --- 2 gather hops (normalization folded in) ---
    k_hop1<<<(kN + 3) / 4, 256, 0, stream>>>(start, ecw, dinv, y, h1, kN);
    k_hop2<<<(kN + 3) / 4, 256, 0, stream>>>(start, ecw, dinv, h1, bias,
                                             (float*)d_out, kN);
}

// Round 5
// 244.023 us; speedup vs baseline: 7.4182x; 1.1453x over previous
//
#include <hip/hip_runtime.h>

// SGC: out = A_norm^2 (x W) + bias   (linearity: A^2 x W = A^2 (xW)).
// N=100000 nodes, E=1000000 edges, D=64 features, fp32 in/out.
// CSR build (counting sort, int atomics only) -> atomic-free gather hops.
// Intermediates y=xW and h1 in bf16. Hops software-pipeline the ecw edge
// stream (next-batch prefetch) to break the ecw->gather dependent chain.

constexpr int kN = 100000;
constexpr int kD = 64;

__device__ __forceinline__ float bf2f(unsigned short u) {
    return __uint_as_float(((unsigned)u) << 16);
}
__device__ __forceinline__ unsigned short f2bf(float f) {  // RNE
    unsigned b = __float_as_uint(f);
    b += 0x7FFF + ((b >> 16) & 1);
    return (unsigned short)(b >> 16);
}

__global__ void k_zero(int* __restrict__ c, int n) {
    int i = blockIdx.x * blockDim.x + threadIdx.x;
    if (i < n) c[i] = 0;
}

// counts[row]++ ; 4 edges per thread via int4 loads, independent atomics
__global__ void k_count(const int* __restrict__ row, int* __restrict__ counts, int E) {
    int t = blockIdx.x * blockDim.x + threadIdx.x;
    int e = t * 4;
    if (e + 3 < E) {
        int4 r = *reinterpret_cast<const int4*>(row + e);
        atomicAdd(&counts[r.x], 1);
        atomicAdd(&counts[r.y], 1);
        atomicAdd(&counts[r.z], 1);
        atomicAdd(&counts[r.w], 1);
    } else {
        for (int k = 0; k < 4 && e + k < E; ++k) atomicAdd(&counts[row[e + k]], 1);
    }
}

// ---- hierarchical exclusive scan of counts (N=100k, chunk=1024) ----
__global__ __launch_bounds__(1024) void k_scan1(const int* __restrict__ counts,
                                                int* __restrict__ excl,
                                                int* __restrict__ partials, int n) {
    __shared__ int sh[1024];
    int t = threadIdx.x;
    int i = blockIdx.x * 1024 + t;
    int v = (i < n) ? counts[i] : 0;
    sh[t] = v;
    __syncthreads();
    for (int off = 1; off < 1024; off <<= 1) {
        int add = (t >= off) ? sh[t - off] : 0;
        __syncthreads();
        sh[t] += add;
        __syncthreads();
    }
    if (i < n) excl[i] = sh[t] - v;               // exclusive within chunk
    if (t == 1023) partials[blockIdx.x] = sh[t];  // chunk total
}

// parallel exclusive scan of the (<=128) chunk totals, one block
__global__ __launch_bounds__(128) void k_scan2(int* __restrict__ partials, int nb) {
    __shared__ int sh[128];
    int t = threadIdx.x;
    int v = (t < nb) ? partials[t] : 0;
    sh[t] = v;
    __syncthreads();
    for (int off = 1; off < 128; off <<= 1) {
        int add = (t >= off) ? sh[t - off] : 0;
        __syncthreads();
        sh[t] += add;
        __syncthreads();
    }
    if (t < nb) partials[t] = sh[t] - v;  // exclusive
}

__global__ __launch_bounds__(1024) void k_scan3(int* __restrict__ excl,
                                                const int* __restrict__ partials,
                                                int* __restrict__ cursor, int n, int E) {
    int i = blockIdx.x * 1024 + threadIdx.x;
    if (i < n) {
        int v = excl[i] + partials[blockIdx.x];
        excl[i] = v;
        cursor[i] = v;
    }
    if (i == 0) excl[n] = E;  // start[kN] = E
}

// place each edge into its destination bucket: ecw[pos] = {col, raw w}
// 2 edges per thread for extra memory-level parallelism on the atomics.
__global__ void k_scatter(const int* __restrict__ row, const int* __restrict__ col,
                          const float* __restrict__ w, int* __restrict__ cursor,
                          int2* __restrict__ ecw, int E) {
    int t = blockIdx.x * blockDim.x + threadIdx.x;
    int e0 = t * 2;
    if (e0 >= E) return;
    int r0 = row[e0];
    int p0 = atomicAdd(&cursor[r0], 1);
    int e1 = e0 + 1;
    if (e1 < E) {
        int r1 = row[e1];
        int p1 = atomicAdd(&cursor[r1], 1);
        int2 v1;
        v1.x = col[e1];
        v1.y = __float_as_int(w[e1]);
        ecw[p1] = v1;
    }
    int2 v0;
    v0.x = col[e0];
    v0.y = __float_as_int(w[e0]);
    ecw[p0] = v0;
}

// per node: deg = 1 + sum of raw w in its bucket; dinv = rsqrt(deg)
__global__ void k_deg(const int* __restrict__ start, const int2* __restrict__ ecw,
                      float* __restrict__ dinv, int n) {
    int i = blockIdx.x * blockDim.x + threadIdx.x;
    if (i >= n) return;
    int s = start[i], e = start[i + 1];
    float d = 1.0f;
    for (int j = s; j < e; ++j) d += __int_as_float(ecw[j].y);
    dinv[i] = (d > 0.0f) ? rsqrtf(d) : 0.0f;
}

// y = x @ W  (fp32 in, bf16 out). thread = row, W staged in LDS.
__global__ __launch_bounds__(256) void k_xw(const float* __restrict__ x,
                                            const float* __restrict__ W,
                                            unsigned short* __restrict__ y, int n) {
    __shared__ float Ws[kD * kD];
    for (int i = threadIdx.x; i < kD * kD; i += 256) Ws[i] = W[i];
    __syncthreads();
    int r = blockIdx.x * 256 + threadIdx.x;
    if (r >= n) return;
    float hr[kD];
    const float4* hp = reinterpret_cast<const float4*>(x + (size_t)r * kD);
#pragma unroll
    for (int k4 = 0; k4 < kD / 4; ++k4) {
        float4 v = hp[k4];
        hr[k4 * 4 + 0] = v.x;
        hr[k4 * 4 + 1] = v.y;
        hr[k4 * 4 + 2] = v.z;
        hr[k4 * 4 + 3] = v.w;
    }
    ushort4* op = reinterpret_cast<ushort4*>(y + (size_t)r * kD);
#pragma unroll
    for (int jb = 0; jb < kD / 4; ++jb) {
        float a0 = 0.0f, a1 = 0.0f, a2 = 0.0f, a3 = 0.0f;
#pragma unroll
        for (int k = 0; k < kD; ++k) {
            float hv = hr[k];
            a0 = fmaf(hv, Ws[k * kD + jb * 4 + 0], a0);
            a1 = fmaf(hv, Ws[k * kD + jb * 4 + 1], a1);
            a2 = fmaf(hv, Ws[k * kD + jb * 4 + 2], a2);
            a3 = fmaf(hv, Ws[k * kD + jb * 4 + 3], a3);
        }
        ushort4 o;
        o.x = f2bf(a0); o.y = f2bf(a1); o.z = f2bf(a2); o.w = f2bf(a3);
        op[jb] = o;
    }
}

// Software-pipelined gather hop body. 1 wave/node, lane=feature.
// acc = dinv[i]*h[i] + sum_j (w_j*dinv[col_j])*h[col_j]; caller scales by di.
template <typename OutWriter>
__device__ __forceinline__ void hop_body(const int* __restrict__ start,
                                         const int2* __restrict__ ecw,
                                         const float* __restrict__ dinv,
                                         const unsigned short* __restrict__ h_in,
                                         int n, OutWriter writeout) {
    int node = blockIdx.x * 4 + (threadIdx.x >> 6);
    int lane = threadIdx.x & 63;
    if (node >= n) return;  // wave-uniform (1 wave = 1 node)
    float di = dinv[node];
    float self = bf2f(h_in[(size_t)node * kD + lane]);  // independent, issues early
    float acc = di * self;
    int s = start[node], e = start[node + 1];
    int j = s;
    int rem = e - s;
    int2 a0, a1, a2, a3;
    if (rem >= 4) { a0 = ecw[j]; a1 = ecw[j + 1]; a2 = ecw[j + 2]; a3 = ecw[j + 3]; }
    while (rem >= 4) {
        int jn = j + 4;
        int remn = rem - 4;
        int2 b0, b1, b2, b3;
        if (remn >= 4) {  // prefetch next batch; latency hidden under gathers below
            b0 = ecw[jn]; b1 = ecw[jn + 1]; b2 = ecw[jn + 2]; b3 = ecw[jn + 3];
        } else {
            b0 = b1 = b2 = b3 = make_int2(0, 0);
        }
        float g0 = bf2f(h_in[(size_t)a0.x * kD + lane]);
        float g1 = bf2f(h_in[(size_t)a1.x * kD + lane]);
        float g2 = bf2f(h_in[(size_t)a2.x * kD + lane]);
        float g3 = bf2f(h_in[(size_t)a3.x * kD + lane]);
        float w0 = __int_as_float(a0.y) * dinv[a0.x];
        float w1 = __int_as_float(a1.y) * dinv[a1.x];
        float w2 = __int_as_float(a2.y) * dinv[a2.x];
        float w3 = __int_as_float(a3.y) * dinv[a3.x];
        acc = fmaf(w0, g0, acc);
        acc = fmaf(w1, g1, acc);
        acc = fmaf(w2, g2, acc);
        acc = fmaf(w3, g3, acc);
        a0 = b0; a1 = b1; a2 = b2; a3 = b3;
        j = jn; rem = remn;
    }
    for (; rem > 0; --rem, ++j) {
        int2 v = ecw[j];
        acc = fmaf(__int_as_float(v.y) * dinv[v.x],
                   bf2f(h_in[(size_t)v.x * kD + lane]), acc);
    }
    writeout(node, lane, di, acc);
}

// hop1: h_out(bf16)
__global__ __launch_bounds__(256) void k_hop1(const int* __restrict__ start,
                                              const int2* __restrict__ ecw,
                                              const float* __restrict__ dinv,
                                              const unsigned short* __restrict__ h_in,
                                              unsigned short* __restrict__ h_out, int n) {
    hop_body(start, ecw, dinv, h_in, n,
             [=](int node, int lane, float di, float acc) {
                 h_out[(size_t)node * kD + lane] = f2bf(di * acc);
             });
}

// hop2: out(fp32) + bias
__global__ __launch_bounds__(256) void k_hop2(const int* __restrict__ start,
                                              const int2* __restrict__ ecw,
                                              const float* __restrict__ dinv,
                                              const unsigned short* __restrict__ h_in,
                                              const float* __restrict__ bias,
                                              float* __restrict__ out, int n) {
    hop_body(start, ecw, dinv, h_in, n,
             [=](int node, int lane, float di, float acc) {
                 out[(size_t)node * kD + lane] = fmaf(di, acc, bias[lane]);
             });
}

extern "C" void kernel_launch(void* const* d_in, const int* in_sizes, int n_in,
                              void* d_out, int out_size, void* d_ws, size_t ws_size,
                              hipStream_t stream) {
    const float* x    = (const float*)d_in[0];   // (N, 64)
    const int*   ei   = (const int*)d_in[1];     // (2, E)
    const float* ew   = (const float*)d_in[2];   // (E,)
    const float* W    = (const float*)d_in[3];   // (64, 64)
    const float* bias = (const float*)d_in[4];   // (64,)
    const int E = in_sizes[1] / 2;
    const int* row = ei;       // destination
    const int* col = ei + E;   // source

    // ws layout (1KB-aligned): counts[kN] | start[kN+1] | cursor[kN] |
    // partials[128] | dinv[kN] | ecw[E] int2 | y bf16 | h1 bf16   (~35 MB)
    char* ws = (char*)d_ws;
    auto alloc = [&](size_t bytes) {
        char* p = ws;
        ws += ((bytes + 1023) & ~(size_t)1023);
        return p;
    };
    int*            counts  = (int*)alloc(sizeof(int) * kN);
    int*            start   = (int*)alloc(sizeof(int) * (kN + 1));
    int*            cursor  = (int*)alloc(sizeof(int) * kN);
    int*            partial = (int*)alloc(sizeof(int) * 128);
    float*          dinv    = (float*)alloc(sizeof(float) * kN);
    int2*           ecw     = (int2*)alloc(sizeof(int2) * (size_t)E);
    unsigned short* y       = (unsigned short*)alloc(sizeof(short) * (size_t)kN * kD);
    unsigned short* h1      = (unsigned short*)alloc(sizeof(short) * (size_t)kN * kD);

    const int NB = (kN + 1023) / 1024;  // 98 scan chunks (<=128 for k_scan2)

    // --- dense linear first: y = x @ W (bf16) ---
    k_xw<<<(kN + 255) / 256, 256, 0, stream>>>(x, W, y, kN);

    // --- CSR build ---
    k_zero<<<(kN + 255) / 256, 256, 0, stream>>>(counts, kN);
    k_count<<<(E / 4 + 255) / 256, 256, 0, stream>>>(row, counts, E);
    k_scan1<<<NB, 1024, 0, stream>>>(counts, start, partial, kN);
    k_scan2<<<1, 128, 0, stream>>>(partial, NB);
    k_scan3<<<NB, 1024, 0, stream>>>(start, partial, cursor, kN, E);
    k_scatter<<<(E / 2 + 255) / 256, 256, 0, stream>>>(row, col, ew, cursor, ecw, E);
    k_deg<<<(kN + 255) / 256, 256, 0, stream>>>(start, ecw, dinv, kN);

    // --- 2 gather hops (normalization folded in) ---
    k_hop1<<<(kN + 3) / 4, 256, 0, stream>>>(start, ecw, dinv, y, h1, kN);
    k_hop2<<<(kN + 3) / 4, 256, 0, stream>>>(start, ecw, dinv, h1, bias,
                                             (float*)d_out, kN);
}